// Round 1
// baseline (5686.134 us; speedup 1.0000x reference)
//
#include <hip/hip_runtime.h>
#include <stdint.h>

#define Bsz 1024
#define Tsz 200
#define Esz 100
#define Hsz 200
#define NITEMS 100000
#define G3 600              // 3*H

#define JT 13               // N-tiles per gate: 13*16 = 208 >= 200
#define KTI 4               // K-tiles for Wi: 4*32 = 128 >= 100
#define KTH 7               // K-tiles for Wh: 7*32 = 224 >= 200
#define WI_FRAGS (Tsz*JT*KTI*3)     // 31200 frags (1KB each)
#define WH_FRAGS (Tsz*JT*KTH*3)     // 54600 frags
#define WI_T_STRIDE (JT*KTI*3*512)  // ushorts per timestep
#define WH_T_STRIDE (JT*KTH*3*512)

typedef __attribute__((ext_vector_type(8))) unsigned short us8;
typedef __attribute__((ext_vector_type(8))) __bf16 bf16x8;
typedef __attribute__((ext_vector_type(4))) float fx4;

static __device__ __forceinline__ unsigned short f2bf(float f) {
  unsigned int u = __float_as_uint(f);
  u += 0x7FFFu + ((u >> 16) & 1u);       // RNE
  return (unsigned short)(u >> 16);
}
static __device__ __forceinline__ fx4 MFMA(us8 a, us8 b, fx4 c) {
  return __builtin_amdgcn_mfma_f32_16x16x32_bf16(
      __builtin_bit_cast(bf16x8, a), __builtin_bit_cast(bf16x8, b), c, 0, 0, 0);
}
static __device__ __forceinline__ float sigm(float x) {
  return 1.0f / (1.0f + __expf(-x));
}
static __device__ __forceinline__ float tanh_f(float x) {
  return 1.0f - 2.0f / (1.0f + __expf(2.0f * x));  // exact limits at +-inf
}

// ---------------------------------------------------------------------------
// Kernel 1: pack Wi/Wh (f32) -> bf16 in MFMA B-fragment order, zero-padded.
// Fragment f index: ((t*13 + j)*nkt + kt)*3 + g ; lane holds B[k0+(l>>4)*8+e][n0+(l&15)]
// Also zeroes the hT staging buffer (so its K-pad cols 200..223 are 0).
// ---------------------------------------------------------------------------
__global__ __launch_bounds__(256) void k_convert(
    const float* __restrict__ Wi, const float* __restrict__ Wh,
    unsigned short* __restrict__ wiB, unsigned short* __restrict__ whB,
    unsigned short* __restrict__ hT)
{
  const int lane = threadIdx.x & 63;
  const int cl = lane & 15, kg = lane >> 4;
  const int wid = blockIdx.x * (blockDim.x >> 6) + (threadIdx.x >> 6);
  const int nw = gridDim.x * (blockDim.x >> 6);

  for (int fi = wid; fi < WI_FRAGS + WH_FRAGS; fi += nw) {
    const bool isWi = fi < WI_FRAGS;
    const int f  = isWi ? fi : fi - WI_FRAGS;
    const int nkt = isWi ? KTI : KTH;
    const int kmax = isWi ? Esz : Hsz;
    const int g  = f % 3;
    const int f2 = f / 3;
    const int kt = f2 % nkt;
    const int f3 = f2 / nkt;
    const int j  = f3 % JT;
    const int t  = f3 / JT;
    const int cloc = j * 16 + cl;
    const bool cok = cloc < Hsz;
    const int col = g * Hsz + cloc;
    const float* src = isWi ? (Wi + (size_t)t * Esz * G3)
                            : (Wh + (size_t)t * Hsz * G3);
    const int k0 = kt * 32 + kg * 8;
    us8 v;
    #pragma unroll
    for (int e = 0; e < 8; e++) {
      int k = k0 + e;
      float x = (cok && k < kmax) ? src[(size_t)k * G3 + col] : 0.0f;
      v[e] = f2bf(x);
    }
    unsigned short* dst = (isWi ? wiB : whB) + (size_t)f * 512 + lane * 8;
    *(us8*)dst = v;   // 16B coalesced store, 1KB per wave
  }

  for (size_t i = (size_t)blockIdx.x * blockDim.x + threadIdx.x;
       i < (size_t)Bsz * 224 / 8;
       i += (size_t)gridDim.x * blockDim.x) {
    ((us8*)hT)[i] = (us8){0, 0, 0, 0, 0, 0, 0, 0};
  }
}

// ---------------------------------------------------------------------------
// Kernel 2: fused embed-gather + GRU scan. 32 blocks x 32 batch rows x 512 thr.
// Per step: x = embed_q[q]*embed_f[f] (bf16, LDS, XOR-swizzled); 8 waves own
// (mt,j) 16x16 output tiles; gi/gh via mfma_16x16x32_bf16 with B-frags
// streamed from the packed weights (L2-resident); gates in fp32 registers.
// One __syncthreads per step; x and h double-buffered in LDS.
// ---------------------------------------------------------------------------
__global__ __launch_bounds__(512, 2) void k_gru(
    const int* __restrict__ q, const int* __restrict__ fidx,
    const float* __restrict__ eq, const float* __restrict__ ef,
    const float* __restrict__ carry, const float* __restrict__ bi,
    const float* __restrict__ bhn,
    const unsigned short* __restrict__ wiB,
    const unsigned short* __restrict__ whB,
    unsigned short* __restrict__ hT)
{
  __shared__ __align__(16) unsigned short xl[2][32][128];  // 16 KB
  __shared__ __align__(16) unsigned short hl[2][32][256];  // 32 KB
  const int tid = threadIdx.x;
  const int lane = tid & 63, wv = tid >> 6;
  const int cl = lane & 15, kg = lane >> 4;
  const int b0 = blockIdx.x * 32;

  float hreg[4][4];   // per owned tile: 4 fp32 h values (C/D rows kg*4+i)

  // prologue: init LDS (XOR swizzle: 16B chunk index ^= row&7 -> bank-spread)
  for (int idx = tid; idx < 2 * 32 * 256; idx += 512) {
    int buf = idx >> 13, rem = idx & 8191;
    int row = rem >> 8, col = rem & 255;
    float v = (col < Hsz) ? carry[col] : 0.0f;
    int ch = (col >> 3) ^ (row & 7);
    hl[buf][row][ch * 8 + (col & 7)] = f2bf(v);
  }
  for (int idx = tid; idx < 2 * 32 * 128; idx += 512) {
    int buf = idx >> 12, rem = idx & 4095;
    int row = rem >> 7, col = rem & 127;
    int ch = (col >> 3) ^ (row & 7);
    xl[buf][row][ch * 8 + (col & 7)] = 0;
  }
  #pragma unroll
  for (int pp = 0; pp < 4; pp++) {
    int p = wv + pp * 8;
    float v = 0.0f;
    if (p < 26) {
      int c = (p % 13) * 16 + cl;
      v = (c < Hsz) ? carry[c] : 0.0f;
    }
    #pragma unroll
    for (int i = 0; i < 4; i++) hreg[pp][i] = v;
  }
  __syncthreads();

  auto gather = [&](int tt, int buf) {
    int row = tid >> 4, s = tid & 15;               // 32 rows x 16 threads
    int qi = q[(b0 + row) * Tsz + tt];
    int fi = fidx[(b0 + row) * Tsz + tt];
    const float* eqp = eq + (size_t)qi * Esz;
    const float* efp = ef + (size_t)fi * Esz;
    #pragma unroll
    for (int u = 0; u < 7; u++) {
      int e = s * 7 + u;
      if (e < Esz) {
        float v = eqp[e] * efp[e];
        int ch = (e >> 3) ^ (row & 7);
        xl[buf][row][ch * 8 + (e & 7)] = f2bf(v);
      }
    }
  };

  gather(0, 0);
  __syncthreads();

  for (int t = 0; t < Tsz; t++) {
    const int rb = t & 1, wb = rb ^ 1;
    if (t + 1 < Tsz) gather(t + 1, wb);            // prefetch next x

    const unsigned short* wit = wiB + (size_t)t * WI_T_STRIDE;
    const unsigned short* wht = whB + (size_t)t * WH_T_STRIDE;

    #pragma unroll
    for (int pp = 0; pp < 4; pp++) {
      int p = wv + pp * 8;
      if (p >= 26) continue;                        // wave-uniform
      const int j = p % 13, mt = p / 13;
      const int row = mt * 16 + cl;                 // A-operand M row
      const int c = j * 16 + cl;                    // gate-relative column
      const bool cok = c < Hsz;

      fx4 ai[3], ah[3];
      #pragma unroll
      for (int g = 0; g < 3; g++) {
        float bv = cok ? bi[t * G3 + g * Hsz + c] : 0.0f;
        ai[g] = (fx4){bv, bv, bv, bv};
        ah[g] = (fx4){0.0f, 0.0f, 0.0f, 0.0f};
      }
      {
        const unsigned short* bp = wit + (size_t)(j * KTI * 3) * 512 + lane * 8;
        #pragma unroll
        for (int kt = 0; kt < KTI; kt++) {
          int ch = (kt * 4 + kg) ^ (row & 7);
          us8 a = *(const us8*)&xl[rb][row][ch * 8];
          #pragma unroll
          for (int g = 0; g < 3; g++) {
            us8 b = *(const us8*)(bp + (kt * 3 + g) * 512);
            ai[g] = MFMA(a, b, ai[g]);
          }
        }
      }
      {
        const unsigned short* bp = wht + (size_t)(j * KTH * 3) * 512 + lane * 8;
        #pragma unroll
        for (int kt = 0; kt < KTH; kt++) {
          int ch = (kt * 4 + kg) ^ (row & 7);
          us8 a = *(const us8*)&hl[rb][row][ch * 8];
          #pragma unroll
          for (int g = 0; g < 3; g++) {
            us8 b = *(const us8*)(bp + (kt * 3 + g) * 512);
            ah[g] = MFMA(a, b, ah[g]);
          }
        }
      }
      float bhnc = cok ? bhn[t * Hsz + c] : 0.0f;
      #pragma unroll
      for (int i = 0; i < 4; i++) {
        float r = sigm(ai[0][i] + ah[0][i]);
        float z = sigm(ai[1][i] + ah[1][i]);
        float n = tanh_f(ai[2][i] + r * (ah[2][i] + bhnc));
        float h = hreg[pp][i];
        h = n + z * (h - n);                        // (1-z)*n + z*h
        hreg[pp][i] = h;
        if (cok) {
          int wrow = mt * 16 + kg * 4 + i;          // C/D row mapping
          int ch2 = (c >> 3) ^ (wrow & 7);
          hl[wb][wrow][ch2 * 8 + (c & 7)] = f2bf(h);
        }
      }
    }
    __syncthreads();
  }

  // epilogue: hT (bf16 [1024][224], pad cols pre-zeroed by k_convert)
  #pragma unroll
  for (int pp = 0; pp < 4; pp++) {
    int p = wv + pp * 8;
    if (p >= 26) continue;
    const int j = p % 13, mt = p / 13;
    const int c = j * 16 + cl;
    if (c < Hsz) {
      #pragma unroll
      for (int i = 0; i < 4; i++) {
        int r = b0 + mt * 16 + kg * 4 + i;
        hT[(size_t)r * 224 + c] = f2bf(hreg[pp][i]);
      }
    }
  }
}

// ---------------------------------------------------------------------------
// Kernel 3: out = hT @ Wout + bout.  Block tile 256(M) x 128(N), K=200 (pad 224).
// Wout staged transposed->bf16 in LDS [128][232] (bank step 20 -> 2-way, free);
// A-frags straight from global (hT is L2-hot, 16B per lane).
// ---------------------------------------------------------------------------
__global__ __launch_bounds__(512, 2) void k_out(
    const unsigned short* __restrict__ hT,
    const float* __restrict__ Wout, const float* __restrict__ bout,
    float* __restrict__ out)
{
  __shared__ __align__(16) unsigned short bl[128][232];   // 59.4 KB
  const int tid = threadIdx.x;
  const int lane = tid & 63, wv = tid >> 6;
  const int cl = lane & 15, kg = lane >> 4;
  const int n0 = blockIdx.x * 128;
  const int m0 = blockIdx.y * 256;

  if (n0 + 128 <= NITEMS) {
    for (int idx = tid; idx < Hsz * 32; idx += 512) {   // float4 coalesced
      int k = idx >> 5, c4 = (idx & 31) * 4;
      const float4 v = *(const float4*)(Wout + (size_t)k * NITEMS + n0 + c4);
      bl[c4 + 0][k] = f2bf(v.x);
      bl[c4 + 1][k] = f2bf(v.y);
      bl[c4 + 2][k] = f2bf(v.z);
      bl[c4 + 3][k] = f2bf(v.w);
    }
  } else {                                              // ragged last block
    for (int idx = tid; idx < Hsz * 128; idx += 512) {
      int k = idx >> 7, c = idx & 127;
      int col = n0 + c;
      float v = (col < NITEMS) ? Wout[(size_t)k * NITEMS + col] : 0.0f;
      bl[c][k] = f2bf(v);
    }
  }
  for (int idx = tid; idx < 128 * 32; idx += 512) {     // zero K-pad 200..231
    int c = idx >> 5, k = 200 + (idx & 31);
    bl[c][k] = 0;
  }
  __syncthreads();

  us8 af[2][7];
  const int mrow = m0 + wv * 32;
  #pragma unroll
  for (int mt = 0; mt < 2; mt++)
    #pragma unroll
    for (int kt = 0; kt < 7; kt++)
      af[mt][kt] = *(const us8*)(hT + (size_t)(mrow + mt * 16 + cl) * 224 +
                                 kt * 32 + kg * 8);

  #pragma unroll
  for (int nt = 0; nt < 8; nt++) {
    fx4 a0 = {0, 0, 0, 0}, a1 = {0, 0, 0, 0};
    #pragma unroll
    for (int kt = 0; kt < 7; kt++) {
      us8 b = *(const us8*)&bl[nt * 16 + cl][kt * 32 + kg * 8];
      a0 = MFMA(af[0][kt], b, a0);
      a1 = MFMA(af[1][kt], b, a1);
    }
    int col = n0 + nt * 16 + cl;
    if (col < NITEMS) {
      float bo = bout[col];
      #pragma unroll
      for (int i = 0; i < 4; i++) {
        out[(size_t)(mrow + kg * 4 + i) * NITEMS + col] = a0[i] + bo;
        out[(size_t)(mrow + 16 + kg * 4 + i) * NITEMS + col] = a1[i] + bo;
      }
    }
  }
}

// ---------------------------------------------------------------------------
extern "C" void kernel_launch(void* const* d_in, const int* in_sizes, int n_in,
                              void* d_out, int out_size, void* d_ws, size_t ws_size,
                              hipStream_t stream)
{
  const int*   q     = (const int*)d_in[0];
  const int*   f     = (const int*)d_in[1];
  const float* eq    = (const float*)d_in[2];
  const float* ef    = (const float*)d_in[3];
  const float* carry = (const float*)d_in[4];
  const float* Wi    = (const float*)d_in[5];
  const float* bi    = (const float*)d_in[6];
  const float* Wh    = (const float*)d_in[7];
  const float* bhn   = (const float*)d_in[8];
  const float* Wout  = (const float*)d_in[9];
  const float* bout  = (const float*)d_in[10];

  // Packed bf16 weights staged INSIDE d_out (86.2 MB of 409.6 MB); k_out
  // overwrites the whole output afterwards, and never reads d_out. Only the
  // tiny hT buffer (459 KB) lives in d_ws.
  unsigned short* wiB = (unsigned short*)d_out;
  unsigned short* whB = wiB + (size_t)WI_FRAGS * 512;
  unsigned short* hT  = (unsigned short*)d_ws;

  k_convert<<<512, 256, 0, stream>>>(Wi, Wh, wiB, whB, hT);
  k_gru<<<32, 512, 0, stream>>>(q, f, eq, ef, carry, bi, bhn, wiB, whB, hT);
  k_out<<<dim3(782, 4), 512, 0, stream>>>(hT, Wout, bout, (float*)d_out);
}

// Round 2
// 2645.582 us; speedup vs baseline: 2.1493x; 2.1493x over previous
//
#include <hip/hip_runtime.h>
#include <stdint.h>

#define Bsz 1024
#define Tsz 200
#define Esz 100
#define Hsz 200
#define NITEMS 100000
#define G3 600

#define JT 13                 // N16 tiles per gate (13*16=208>=200)
#define KTI 4                 // K32 tiles for E=100 (pad 128)
#define KTH 7                 // K32 tiles for H=200 (pad 224)
#define GI_LD 608             // padded gi row: 3*200 + 8

#define WI_FRAGS (Tsz*JT*3*KTI)   // 31200 frags of 1KB
#define WH_FRAGS (Tsz*JT*KTH*3)   // 54600 frags of 1KB

typedef __attribute__((ext_vector_type(8))) unsigned short us8;
typedef __attribute__((ext_vector_type(4))) unsigned short us4;
typedef __attribute__((ext_vector_type(8))) __bf16 bf16x8;
typedef __attribute__((ext_vector_type(4))) float fx4;

static __device__ __forceinline__ unsigned short f2bf(float f) {
  unsigned int u = __float_as_uint(f);
  u += 0x7FFFu + ((u >> 16) & 1u);       // RNE
  return (unsigned short)(u >> 16);
}
static __device__ __forceinline__ float bf2f(unsigned short u) {
  return __uint_as_float(((unsigned int)u) << 16);
}
static __device__ __forceinline__ fx4 MFMA(us8 a, us8 b, fx4 c) {
  return __builtin_amdgcn_mfma_f32_16x16x32_bf16(
      __builtin_bit_cast(bf16x8, a), __builtin_bit_cast(bf16x8, b), c, 0, 0, 0);
}
static __device__ __forceinline__ float sigm(float x) {
  return 1.0f / (1.0f + __expf(-x));
}
static __device__ __forceinline__ float tanh_f(float x) {
  return 1.0f - 2.0f / (1.0f + __expf(2.0f * x));
}

// ---------------------------------------------------------------------------
// k_pack: Wi/Wh f32 -> bf16 MFMA B-fragments, via coalesced row reads + LDS
// transpose. Block = (t, kt-slab of 32 K-rows). Also zeroes hT.
// Wi frag idx: ((t*13+j)*3+g)*4+kt   (k_gi order: (j,g) outer, kt inner)
// Wh frag idx: ((t*13+j)*7+kt)*3+g   (k_seq order: kt outer, g inner)
// ---------------------------------------------------------------------------
__global__ __launch_bounds__(256) void k_pack(
    const float* __restrict__ Wi, const float* __restrict__ Wh,
    unsigned short* __restrict__ wiB, unsigned short* __restrict__ whB,
    unsigned short* __restrict__ hT)
{
  __shared__ __align__(16) unsigned short st[32][608];
  const int bid = blockIdx.x;
  const int t = bid / 11, u = bid % 11;
  const bool isWi = u < KTI;
  const int kt = isWi ? u : u - KTI;
  const int kmax = isWi ? Esz : Hsz;
  const float* src = isWi ? (Wi + (size_t)t * Esz * G3)
                          : (Wh + (size_t)t * Hsz * G3);
  const int tid = threadIdx.x;

  for (int idx = tid; idx < 32 * 150; idx += 256) {
    int rr = idx / 150, cc = (idx % 150) * 4;
    int k = kt * 32 + rr;
    float4 v = (k < kmax) ? *(const float4*)(src + (size_t)k * G3 + cc)
                          : make_float4(0.f, 0.f, 0.f, 0.f);
    st[rr][cc + 0] = f2bf(v.x); st[rr][cc + 1] = f2bf(v.y);
    st[rr][cc + 2] = f2bf(v.z); st[rr][cc + 3] = f2bf(v.w);
  }
  __syncthreads();

  const int lane = tid & 63, wv = tid >> 6;
  const int cl = lane & 15, kg = lane >> 4;
  for (int fr = wv; fr < JT * 3; fr += 4) {
    int j = fr / 3, g = fr % 3;
    int cloc = j * 16 + cl;
    us8 v;
    #pragma unroll
    for (int e = 0; e < 8; e++)
      v[e] = (cloc < Hsz) ? st[kg * 8 + e][g * Hsz + cloc] : (unsigned short)0;
    size_t fi = isWi ? (size_t)(((t * JT + j) * 3 + g) * KTI + kt)
                     : (size_t)(((t * JT + j) * KTH + kt) * 3 + g);
    unsigned short* dst = (isWi ? wiB : whB) + fi * 512 + lane * 8;
    *(us8*)dst = v;
  }

  {   // zero hT [1024][224] bf16 (pad cols must be 0 for k_out)
    int idx = bid * 256 + tid;
    if (idx < Bsz * 224 / 8) ((us8*)hT)[idx] = (us8){0, 0, 0, 0, 0, 0, 0, 0};
  }
}

// ---------------------------------------------------------------------------
// k_gi: GI[t][b][608] = embed_q[q]*embed_f[f] @ Wi_t + bi_t  (bf16, all t in
// parallel). Block = (256-row chunk, t); gather fused via LDS-staged X.
// ---------------------------------------------------------------------------
__global__ __launch_bounds__(512, 2) void k_gi(
    const int* __restrict__ q, const int* __restrict__ fidx,
    const float* __restrict__ eq, const float* __restrict__ ef,
    const float* __restrict__ bi,
    const unsigned short* __restrict__ wiB,
    unsigned short* __restrict__ GI)
{
  __shared__ __align__(16) unsigned short x[256][128];   // 64 KB, XOR-swizzled
  const int t = blockIdx.y, mc = blockIdx.x;
  const int tid = threadIdx.x;
  {
    const int row = tid >> 1, half = tid & 1;
    const int row_g = mc * 256 + row;
    const int qi = q[(size_t)row_g * Tsz + t];
    const int fi = fidx[(size_t)row_g * Tsz + t];
    const float* eqp = eq + (size_t)qi * Esz;
    const float* efp = ef + (size_t)fi * Esz;
    if (half == 0) {
      #pragma unroll
      for (int ii = 0; ii < 13; ii++) {
        float4 a = *(const float4*)(eqp + ii * 4);
        float4 b = *(const float4*)(efp + ii * 4);
        int e = ii * 4, ch = (e >> 3) ^ (row & 7);
        us4 w = {f2bf(a.x * b.x), f2bf(a.y * b.y), f2bf(a.z * b.z), f2bf(a.w * b.w)};
        *(us4*)&x[row][ch * 8 + (e & 7)] = w;
      }
    } else {
      #pragma unroll
      for (int ii = 13; ii < 25; ii++) {
        float4 a = *(const float4*)(eqp + ii * 4);
        float4 b = *(const float4*)(efp + ii * 4);
        int e = ii * 4, ch = (e >> 3) ^ (row & 7);
        us4 w = {f2bf(a.x * b.x), f2bf(a.y * b.y), f2bf(a.z * b.z), f2bf(a.w * b.w)};
        *(us4*)&x[row][ch * 8 + (e & 7)] = w;
      }
      #pragma unroll
      for (int e = 100; e < 128; e += 4) {       // K-pad -> 0
        int ch = (e >> 3) ^ (row & 7);
        *(us4*)&x[row][ch * 8 + (e & 7)] = (us4){0, 0, 0, 0};
      }
    }
  }
  for (int idx = tid; idx < 256 * 8; idx += 512) {  // zero GI pad cols 600..607
    int r = idx >> 3, c = 600 + (idx & 7);
    GI[((size_t)t * Bsz + mc * 256 + r) * GI_LD + c] = 0;
  }
  __syncthreads();

  const int lane = tid & 63, wv = tid >> 6;
  const int cl = lane & 15, kg = lane >> 4;
  us8 a[2][KTI];
  #pragma unroll
  for (int m = 0; m < 2; m++) {
    int r = (wv * 2 + m) * 16 + cl;
    #pragma unroll
    for (int kt = 0; kt < KTI; kt++) {
      int ch = (kt * 4 + kg) ^ (r & 7);
      a[m][kt] = *(const us8*)&x[r][ch * 8];
    }
  }
  const unsigned short* wt = wiB + (size_t)t * JT * 3 * KTI * 512 + lane * 8;
  for (int j = 0; j < JT; j++) {
    int cloc = j * 16 + cl;
    bool cok = cloc < Hsz;
    #pragma unroll
    for (int g = 0; g < 3; g++) {
      float bv = cok ? bi[t * G3 + g * Hsz + cloc] : 0.0f;
      fx4 acc0 = {bv, bv, bv, bv}, acc1 = {bv, bv, bv, bv};
      const unsigned short* bp = wt + (size_t)((j * 3 + g) * KTI) * 512;
      #pragma unroll
      for (int kt = 0; kt < KTI; kt++) {
        us8 b = *(const us8*)(bp + kt * 512);
        acc0 = MFMA(a[0][kt], b, acc0);
        acc1 = MFMA(a[1][kt], b, acc1);
      }
      if (cok) {
        int col = g * Hsz + cloc;
        #pragma unroll
        for (int i = 0; i < 4; i++) {
          size_t r0 = (size_t)t * Bsz + mc * 256 + (wv * 2 + 0) * 16 + kg * 4 + i;
          size_t r1 = (size_t)t * Bsz + mc * 256 + (wv * 2 + 1) * 16 + kg * 4 + i;
          GI[r0 * GI_LD + col] = f2bf(acc0[i]);
          GI[r1 * GI_LD + col] = f2bf(acc1[i]);
        }
      }
    }
  }
}

// ---------------------------------------------------------------------------
// k_seq: the sequential GRU scan, gh-only. 32 blocks x 32 rows, 13 waves
// (832 thr); wave j owns the 16-col j-tile for all 3 gates x 2 m-tiles.
// Per step: issue 24 GI loads early; 14 ds_reads (A=h) + 21 B-frag global
// loads (contiguous 21KB/wave, L2/L3-hot) + 42 MFMA; gates in fp32; h
// double-buffered in LDS, ONE barrier/step.
// ---------------------------------------------------------------------------
__global__ __launch_bounds__(832) void k_seq(
    const float* __restrict__ carry, const float* __restrict__ bhn,
    const unsigned short* __restrict__ whB,
    const unsigned short* __restrict__ GI,
    unsigned short* __restrict__ hT)
{
  __shared__ __align__(16) unsigned short h[2][32][256];   // 32 KB
  const int tid = threadIdx.x;
  const int lane = tid & 63, j = tid >> 6;      // wave index == j-tile
  const int cl = lane & 15, kg = lane >> 4;
  const int b0 = blockIdx.x * 32;
  const int cloc = j * 16 + cl;
  const bool cok = cloc < Hsz;

  for (int idx = tid; idx < 2 * 32 * 256; idx += 832) {
    int buf = idx >> 13, rem = idx & 8191;
    int row = rem >> 8, col = rem & 255;
    float v = (col < Hsz) ? carry[col] : 0.0f;
    int ch = (col >> 3) ^ (row & 7);
    h[buf][row][ch * 8 + (col & 7)] = f2bf(v);
  }
  float hreg[2][4];
  {
    float v = cok ? carry[cloc] : 0.0f;
    #pragma unroll
    for (int m = 0; m < 2; m++)
      #pragma unroll
      for (int i = 0; i < 4; i++) hreg[m][i] = v;
  }
  __syncthreads();

  int cur = 0;
  for (int t = 0; t < Tsz; t++) {
    // GI loads issued first; first use is after the MFMA phase (latency hidden)
    unsigned short gi_r[2][4], gi_z[2][4], gi_n[2][4];
    const unsigned short* GIt = GI + (size_t)t * Bsz * GI_LD;
    #pragma unroll
    for (int m = 0; m < 2; m++)
      #pragma unroll
      for (int i = 0; i < 4; i++) {
        const unsigned short* gp = GIt + (size_t)(b0 + m * 16 + kg * 4 + i) * GI_LD;
        gi_r[m][i] = gp[cloc];
        gi_z[m][i] = gp[Hsz + cloc];
        gi_n[m][i] = gp[2 * Hsz + cloc];
      }

    fx4 acc[2][3];
    #pragma unroll
    for (int m = 0; m < 2; m++)
      #pragma unroll
      for (int g = 0; g < 3; g++) acc[m][g] = (fx4){0, 0, 0, 0};

    const unsigned short* wp =
        whB + (size_t)(t * JT + j) * KTH * 3 * 512 + lane * 8;
    #pragma unroll
    for (int kt = 0; kt < KTH; kt++) {
      int ch0 = (kt * 4 + kg) ^ (cl & 7);        // (16+cl)&7 == cl&7
      us8 a0 = *(const us8*)&h[cur][cl][ch0 * 8];
      us8 a1 = *(const us8*)&h[cur][16 + cl][ch0 * 8];
      const unsigned short* bp = wp + (size_t)(kt * 3) * 512;
      #pragma unroll
      for (int g = 0; g < 3; g++) {
        us8 b = *(const us8*)(bp + g * 512);
        acc[0][g] = MFMA(a0, b, acc[0][g]);
        acc[1][g] = MFMA(a1, b, acc[1][g]);
      }
    }

    float bhnc = cok ? bhn[t * Hsz + cloc] : 0.0f;
    const int nxt = cur ^ 1;
    #pragma unroll
    for (int m = 0; m < 2; m++)
      #pragma unroll
      for (int i = 0; i < 4; i++) {
        float r = sigm(bf2f(gi_r[m][i]) + acc[m][0][i]);
        float z = sigm(bf2f(gi_z[m][i]) + acc[m][1][i]);
        float n = tanh_f(bf2f(gi_n[m][i]) + r * (acc[m][2][i] + bhnc));
        float hv = n + z * (hreg[m][i] - n);
        hreg[m][i] = hv;
        if (cok) {
          int wrow = m * 16 + kg * 4 + i;
          int ch2 = (cloc >> 3) ^ (wrow & 7);
          h[nxt][wrow][ch2 * 8 + (cloc & 7)] = f2bf(hv);
        }
      }
    cur = nxt;
    __syncthreads();
  }

  if (cok) {
    #pragma unroll
    for (int m = 0; m < 2; m++)
      #pragma unroll
      for (int i = 0; i < 4; i++)
        hT[(size_t)(b0 + m * 16 + kg * 4 + i) * 224 + cloc] = f2bf(hreg[m][i]);
  }
}

// ---------------------------------------------------------------------------
// k_out: out = hT @ Wout + bout. Unchanged from round 1 (passed).
// ---------------------------------------------------------------------------
__global__ __launch_bounds__(512, 2) void k_out(
    const unsigned short* __restrict__ hT,
    const float* __restrict__ Wout, const float* __restrict__ bout,
    float* __restrict__ out)
{
  __shared__ __align__(16) unsigned short bl[128][232];   // 59.4 KB
  const int tid = threadIdx.x;
  const int lane = tid & 63, wv = tid >> 6;
  const int cl = lane & 15, kg = lane >> 4;
  const int n0 = blockIdx.x * 128;
  const int m0 = blockIdx.y * 256;

  if (n0 + 128 <= NITEMS) {
    for (int idx = tid; idx < Hsz * 32; idx += 512) {
      int k = idx >> 5, c4 = (idx & 31) * 4;
      const float4 v = *(const float4*)(Wout + (size_t)k * NITEMS + n0 + c4);
      bl[c4 + 0][k] = f2bf(v.x);
      bl[c4 + 1][k] = f2bf(v.y);
      bl[c4 + 2][k] = f2bf(v.z);
      bl[c4 + 3][k] = f2bf(v.w);
    }
  } else {
    for (int idx = tid; idx < Hsz * 128; idx += 512) {
      int k = idx >> 7, c = idx & 127;
      int col = n0 + c;
      float v = (col < NITEMS) ? Wout[(size_t)k * NITEMS + col] : 0.0f;
      bl[c][k] = f2bf(v);
    }
  }
  for (int idx = tid; idx < 128 * 32; idx += 512) {
    int c = idx >> 5, k = 200 + (idx & 31);
    bl[c][k] = 0;
  }
  __syncthreads();

  us8 af[2][7];
  const int mrow = m0 + wv * 32;
  #pragma unroll
  for (int mt = 0; mt < 2; mt++)
    #pragma unroll
    for (int kt = 0; kt < 7; kt++)
      af[mt][kt] = *(const us8*)(hT + (size_t)(mrow + mt * 16 + cl) * 224 +
                                 kt * 32 + kg * 8);

  #pragma unroll
  for (int nt = 0; nt < 8; nt++) {
    fx4 a0 = {0, 0, 0, 0}, a1 = {0, 0, 0, 0};
    #pragma unroll
    for (int kt = 0; kt < 7; kt++) {
      us8 b = *(const us8*)&bl[nt * 16 + cl][kt * 32 + kg * 8];
      a0 = MFMA(af[0][kt], b, a0);
      a1 = MFMA(af[1][kt], b, a1);
    }
    int col = n0 + nt * 16 + cl;
    if (col < NITEMS) {
      float bo = bout[col];
      #pragma unroll
      for (int i = 0; i < 4; i++) {
        out[(size_t)(mrow + kg * 4 + i) * NITEMS + col] = a0[i] + bo;
        out[(size_t)(mrow + 16 + kg * 4 + i) * NITEMS + col] = a1[i] + bo;
      }
    }
  }
}

// ---------------------------------------------------------------------------
extern "C" void kernel_launch(void* const* d_in, const int* in_sizes, int n_in,
                              void* d_out, int out_size, void* d_ws, size_t ws_size,
                              hipStream_t stream)
{
  const int*   q     = (const int*)d_in[0];
  const int*   f     = (const int*)d_in[1];
  const float* eq    = (const float*)d_in[2];
  const float* ef    = (const float*)d_in[3];
  const float* carry = (const float*)d_in[4];
  const float* Wi    = (const float*)d_in[5];
  const float* bi    = (const float*)d_in[6];
  const float* Wh    = (const float*)d_in[7];
  const float* bhn   = (const float*)d_in[8];
  const float* Wout  = (const float*)d_in[9];
  const float* bout  = (const float*)d_in[10];

  // d_out staging (dead before k_out overwrites it):
  //   [wiB 31.95 MB][whB 55.91 MB][GI 249.0 MB]  = 336.9 MB < 409.6 MB
  unsigned short* wiB = (unsigned short*)d_out;
  unsigned short* whB = wiB + (size_t)WI_FRAGS * 512;
  unsigned short* GI  = whB + (size_t)WH_FRAGS * 512;
  unsigned short* hT  = (unsigned short*)d_ws;   // 458.75 KB

  k_pack<<<Tsz * 11, 256, 0, stream>>>(Wi, Wh, wiB, whB, hT);
  k_gi<<<dim3(4, Tsz), 512, 0, stream>>>(q, f, eq, ef, bi, wiB, GI);
  k_seq<<<32, 832, 0, stream>>>(carry, bhn, whB, GI, hT);
  k_out<<<dim3(782, 4), 512, 0, stream>>>(hT, Wout, bout, (float*)d_out);
}